// Round 1
// baseline (524.128 us; speedup 1.0000x reference)
//
#include <hip/hip_runtime.h>
#include <hip/hip_fp16.h>

// Problem constants (from reference setup_inputs)
#define TOTAL_RELN 500
#define EMB 256
#define NBATCH 2048
#define KSPLIT 768           // 3 * EMB: [hi|lo|hi] x [hi|hi|lo] split-fp16 GEMM

typedef _Float16 half8 __attribute__((ext_vector_type(8)));
typedef float f32x4 __attribute__((ext_vector_type(4)));

__device__ __forceinline__ void gload_lds16(const void* g, void* l) {
    __builtin_amdgcn_global_load_lds(
        (const __attribute__((address_space(1))) void*)g,
        (__attribute__((address_space(3))) void*)l, 16, 0, 0);
}

// ---------------------------------------------------------------------------
// Kernel 1: gather + diag-scale + fp16 hi/lo split.
//   A'[b] = [ hi(h*r) | lo(h*r) | hi(h*r) ]   (768 halves)
//   B'[c] = [ hi(t)   | hi(t)   | lo(t)   ]
// so that A'.B'^T = (hi_a+lo_a)*hi_b + hi_a*lo_b = hr*t - lo_a*lo_b (~2^-24 rel)
// ---------------------------------------------------------------------------
__global__ __launch_bounds__(EMB) void prep_kernel(
    const int* __restrict__ bh, const int* __restrict__ bt,
    const int* __restrict__ br, const float* __restrict__ ent,
    const float* __restrict__ rel, _Float16* __restrict__ Ap,
    _Float16* __restrict__ Bp) {
    const int b = blockIdx.x;
    const int e = threadIdx.x;
    const int h = bh[b], t = bt[b], r = br[b];

    const float hv = ent[(size_t)h * EMB + e];
    const float rv = rel[(size_t)r * EMB * EMB + (size_t)e * (EMB + 1)]; // diagonal
    const float tv = ent[(size_t)t * EMB + e];
    const float hr = hv * rv;

    const _Float16 a_hi = (_Float16)hr;
    const _Float16 a_lo = (_Float16)(hr - (float)a_hi);
    const _Float16 b_hi = (_Float16)tv;
    const _Float16 b_lo = (_Float16)(tv - (float)b_hi);

    const size_t base = (size_t)b * KSPLIT;
    Ap[base + e]           = a_hi;
    Ap[base + EMB + e]     = a_lo;
    Ap[base + 2 * EMB + e] = a_hi;
    Bp[base + e]           = b_hi;
    Bp[base + EMB + e]     = b_hi;
    Bp[base + 2 * EMB + e] = b_lo;
}

// ---------------------------------------------------------------------------
// Kernel 2: NT GEMM (both operands K-major) 2048x2048x768 f16->f32 + sigmoid.
// m97 structure: 128x128 tile, BK=64, 4 waves, each wave = 64x64 (4x4 frags of
// 16x16x32 MFMA), global_load_lds width-16 staging, single LDS buffer.
// ---------------------------------------------------------------------------
#define BM 128
#define BN 128
#define BK 64

__global__ __launch_bounds__(256) void gemm_sig_kernel(
    const _Float16* __restrict__ Ap, const _Float16* __restrict__ Bp,
    float* __restrict__ out) {
    __shared__ _Float16 As[BM * BK];   // 16 KiB, row-major [row][k]
    __shared__ _Float16 Bs[BN * BK];   // 16 KiB

    const int tid  = threadIdx.x;
    const int wave = tid >> 6;
    const int lane = tid & 63;
    const int bm = blockIdx.y, bn = blockIdx.x;
    const int wr = wave >> 1, wc = wave & 1;   // wave -> 64x64 quadrant

    f32x4 acc[4][4] = {};

    const int l8  = lane >> 3;          // 0..7: row within 8-row group
    const int c16 = (lane & 7) * 16;    // byte offset within 128 B row

    for (int kt = 0; kt < KSPLIT / BK; ++kt) {
        __syncthreads();   // previous tile fully consumed
        const int k0 = kt * BK;
        // Stage A and B tiles: each wave call covers 8 rows x 64 halves (1 KiB).
        #pragma unroll
        for (int rnd = 0; rnd < 4; ++rnd) {
            const int rowbase = rnd * 32 + wave * 8;
            const char* ga = (const char*)(Ap + (size_t)(bm * BM + rowbase + l8) * KSPLIT + k0) + c16;
            gload_lds16(ga, (char*)As + rowbase * (BK * 2));
            const char* gb = (const char*)(Bp + (size_t)(bn * BN + rowbase + l8) * KSPLIT + k0) + c16;
            gload_lds16(gb, (char*)Bs + rowbase * (BK * 2));
        }
        __syncthreads();   // compiler drains vmcnt before s_barrier

        #pragma unroll
        for (int ks = 0; ks < 2; ++ks) {
            half8 af[4], bf[4];
            const int kb = ks * 32 + (lane >> 4) * 8;  // k-offset for this lane
            const int rA = lane & 15;
            #pragma unroll
            for (int m = 0; m < 4; ++m)
                af[m] = *(const half8*)&As[(wr * 64 + m * 16 + rA) * BK + kb];
            #pragma unroll
            for (int n = 0; n < 4; ++n)
                bf[n] = *(const half8*)&Bs[(wc * 64 + n * 16 + rA) * BK + kb];
            #pragma unroll
            for (int m = 0; m < 4; ++m)
                #pragma unroll
                for (int n = 0; n < 4; ++n)
                    acc[m][n] = __builtin_amdgcn_mfma_f32_16x16x32_f16(
                        af[m], bf[n], acc[m][n], 0, 0, 0);
        }
    }

    // Epilogue: sigmoid + store. D layout: col = lane&15, row = (lane>>4)*4 + j.
    const int row0 = bm * BM + wr * 64;
    const int col0 = bn * BN + wc * 64;
    const int rlane = (lane >> 4) * 4;
    const int clane = lane & 15;
    #pragma unroll
    for (int m = 0; m < 4; ++m)
        #pragma unroll
        for (int n = 0; n < 4; ++n)
            #pragma unroll
            for (int j = 0; j < 4; ++j) {
                const float v = acc[m][n][j];
                const float s = 1.0f / (1.0f + expf(-v));
                out[(size_t)(row0 + m * 16 + rlane + j) * NBATCH
                    + (col0 + n * 16 + clane)] = s;
            }
}

extern "C" void kernel_launch(void* const* d_in, const int* in_sizes, int n_in,
                              void* d_out, int out_size, void* d_ws, size_t ws_size,
                              hipStream_t stream) {
    const int*   batch_h = (const int*)d_in[0];
    const int*   batch_t = (const int*)d_in[1];
    const int*   batch_r = (const int*)d_in[2];
    const float* ent_emb = (const float*)d_in[3];
    const float* rel_emb = (const float*)d_in[4];
    float* out = (float*)d_out;

    _Float16* Ap = (_Float16*)d_ws;                          // 2048*768 halves = 3 MiB
    _Float16* Bp = Ap + (size_t)NBATCH * KSPLIT;             // +3 MiB

    prep_kernel<<<NBATCH, EMB, 0, stream>>>(batch_h, batch_t, batch_r,
                                            ent_emb, rel_emb, Ap, Bp);
    gemm_sig_kernel<<<dim3(NBATCH / BN, NBATCH / BM), 256, 0, stream>>>(Ap, Bp, out);
}

// Round 2
// 520.461 us; speedup vs baseline: 1.0070x; 1.0070x over previous
//
#include <hip/hip_runtime.h>
#include <hip/hip_fp16.h>

// Problem constants (from reference setup_inputs)
#define TOTAL_RELN 500
#define EMB 256
#define NBATCH 2048
#define KSPLIT 768           // 3 * EMB: [hi|lo|hi] x [hi|hi|lo] split-fp16 GEMM

typedef _Float16 half8 __attribute__((ext_vector_type(8)));
typedef float f32x4 __attribute__((ext_vector_type(4)));

__device__ __forceinline__ void gload_lds16(const void* g, void* l) {
    __builtin_amdgcn_global_load_lds(
        (const __attribute__((address_space(1))) void*)g,
        (__attribute__((address_space(3))) void*)l, 16, 0, 0);
}

// ---------------------------------------------------------------------------
// Kernel 1 (unchanged from round 1): gather + diag-scale + fp16 hi/lo split.
//   A'[b] = [ hi(h*r) | lo(h*r) | hi(h*r) ]   (768 halves)
//   B'[c] = [ hi(t)   | hi(t)   | lo(t)   ]
// A'.B'^T = hr*t - lo_a*lo_b  (~2^-22 rel residual)
// ---------------------------------------------------------------------------
__global__ __launch_bounds__(EMB) void prep_kernel(
    const int* __restrict__ bh, const int* __restrict__ bt,
    const int* __restrict__ br, const float* __restrict__ ent,
    const float* __restrict__ rel, _Float16* __restrict__ Ap,
    _Float16* __restrict__ Bp) {
    const int b = blockIdx.x;
    const int e = threadIdx.x;
    const int h = bh[b], t = bt[b], r = br[b];

    const float hv = ent[(size_t)h * EMB + e];
    const float rv = rel[(size_t)r * EMB * EMB + (size_t)e * (EMB + 1)]; // diagonal
    const float tv = ent[(size_t)t * EMB + e];
    const float hr = hv * rv;

    const _Float16 a_hi = (_Float16)hr;
    const _Float16 a_lo = (_Float16)(hr - (float)a_hi);
    const _Float16 b_hi = (_Float16)tv;
    const _Float16 b_lo = (_Float16)(tv - (float)b_hi);

    const size_t base = (size_t)b * KSPLIT;
    Ap[base + e]           = a_hi;
    Ap[base + EMB + e]     = a_lo;
    Ap[base + 2 * EMB + e] = a_hi;
    Bp[base + e]           = b_hi;
    Bp[base + EMB + e]     = b_hi;
    Bp[base + 2 * EMB + e] = b_lo;
}

// ---------------------------------------------------------------------------
// Kernel 2 v2: NT GEMM 2048x2048x768 f16->f32 + sigmoid.
// Changes vs round 1:
//   - 512 threads (8 waves, 2 waves/SIMD): wave = 32x64 output (acc 2x4)
//   - 2-phase double-buffered LDS (T3-minimum): stage k+1 before compute k,
//     ONE barrier per K-iter (was 2)
//   - XCD-chunked bijective blockIdx swizzle (grid 256 % 8 == 0)
// ---------------------------------------------------------------------------
#define BM 128
#define BN 128
#define BK 64
#define KTILES (KSPLIT / BK)   // 12

__global__ __launch_bounds__(512) void gemm_sig_kernel(
    const _Float16* __restrict__ Ap, const _Float16* __restrict__ Bp,
    float* __restrict__ out) {
    __shared__ _Float16 As[2][BM * BK];   // 2 x 16 KiB
    __shared__ _Float16 Bs[2][BN * BK];   // 2 x 16 KiB

    const int tid  = threadIdx.x;
    const int wave = tid >> 6;          // 0..7
    const int lane = tid & 63;

    // XCD-chunked swizzle: 256 blocks, 8 XCDs -> 32 contiguous blocks per XCD
    const int bid = blockIdx.x;
    const int swz = (bid & 7) * 32 + (bid >> 3);
    const int bm = swz >> 4, bn = swz & 15;

    const int wr = wave >> 1;           // 0..3 : 32-row band
    const int wc = wave & 1;            // 0..1 : 64-col half

    f32x4 acc[2][4] = {};

    const int l8  = lane >> 3;          // 0..7
    const int c16 = (lane & 7) * 16;    // byte offset within 128 B row

    const _Float16* Abase = Ap + (size_t)(bm * BM) * KSPLIT;
    const _Float16* Bbase = Bp + (size_t)(bn * BN) * KSPLIT;

    // Stage one 128x64 A-tile + B-tile into LDS buffer `buf` (8 waves:
    // each wave covers 8 rows x 128 B per round, 2 rounds per operand).
    auto stage = [&](int buf, int kt) {
        const int k0 = kt * BK;
        #pragma unroll
        for (int rnd = 0; rnd < 2; ++rnd) {
            const int rowbase = rnd * 64 + wave * 8;
            gload_lds16(
                (const char*)(Abase + (size_t)(rowbase + l8) * KSPLIT + k0) + c16,
                (char*)&As[buf][rowbase * BK]);
            gload_lds16(
                (const char*)(Bbase + (size_t)(rowbase + l8) * KSPLIT + k0) + c16,
                (char*)&Bs[buf][rowbase * BK]);
        }
    };

    auto compute = [&](int buf) {
        #pragma unroll
        for (int ks = 0; ks < 2; ++ks) {
            const int kb = ks * 32 + ((lane >> 4) << 3);
            const int rA = lane & 15;
            half8 af[2], bf[4];
            #pragma unroll
            for (int m = 0; m < 2; ++m)
                af[m] = *(const half8*)&As[buf][(wr * 32 + m * 16 + rA) * BK + kb];
            #pragma unroll
            for (int n = 0; n < 4; ++n)
                bf[n] = *(const half8*)&Bs[buf][(wc * 64 + n * 16 + rA) * BK + kb];
            #pragma unroll
            for (int m = 0; m < 2; ++m)
                #pragma unroll
                for (int n = 0; n < 4; ++n)
                    acc[m][n] = __builtin_amdgcn_mfma_f32_16x16x32_f16(
                        af[m], bf[n], acc[m][n], 0, 0, 0);
        }
    };

    stage(0, 0);
    __syncthreads();                    // drains vmcnt before barrier
    int buf = 0;
    for (int kt = 0; kt < KTILES; ++kt) {
        if (kt + 1 < KTILES) stage(buf ^ 1, kt + 1);   // overlap with compute
        compute(buf);
        __syncthreads();                // one barrier per iter
        buf ^= 1;
    }

    // Epilogue: sigmoid + store. D layout: col = lane&15, row = (lane>>4)*4+j.
    const int row0 = bm * BM + wr * 32 + ((lane >> 4) << 2);
    const int col0 = bn * BN + wc * 64 + (lane & 15);
    #pragma unroll
    for (int m = 0; m < 2; ++m)
        #pragma unroll
        for (int n = 0; n < 4; ++n)
            #pragma unroll
            for (int j = 0; j < 4; ++j) {
                const float v = acc[m][n][j];
                const float s = 1.0f / (1.0f + __expf(-v));
                out[(size_t)(row0 + m * 16 + j) * NBATCH + (col0 + n * 16)] = s;
            }
}

extern "C" void kernel_launch(void* const* d_in, const int* in_sizes, int n_in,
                              void* d_out, int out_size, void* d_ws, size_t ws_size,
                              hipStream_t stream) {
    const int*   batch_h = (const int*)d_in[0];
    const int*   batch_t = (const int*)d_in[1];
    const int*   batch_r = (const int*)d_in[2];
    const float* ent_emb = (const float*)d_in[3];
    const float* rel_emb = (const float*)d_in[4];
    float* out = (float*)d_out;

    _Float16* Ap = (_Float16*)d_ws;                          // 2048*768 halves = 3 MiB
    _Float16* Bp = Ap + (size_t)NBATCH * KSPLIT;             // +3 MiB

    prep_kernel<<<NBATCH, EMB, 0, stream>>>(batch_h, batch_t, batch_r,
                                            ent_emb, rel_emb, Ap, Bp);
    gemm_sig_kernel<<<256, 512, 0, stream>>>(Ap, Bp, out);
}